// Round 15
// baseline (894.165 us; speedup 1.0000x reference)
//
#include <hip/hip_runtime.h>
#include <hip/hip_bf16.h>

// MultiSemanticSPR: B=4096, H=1024, S=7
// Round 14:
//  (1) ggemm_k gains template BK in {64,128}. BK=128 used for fusion1
//      (K=7168) and fusion2 (K=2048): half the barrier drains, 2x in-flight
//      staging at their grid-capped 2/1 blocks/CU; LDS 64KB keeps 2/CU.
//      8-slot XOR extended: 8 calls x 4 rows, call-parity pointer pair.
//      K order unchanged -> bit-identical.
//  (2) LN+GELU fused into gs (lngs2_k, packed bf16 V, ~105 VGPR, no forced
//      bounds): removes the 117MB inter-kernel slab round-trip.
// Everything else identical to R13.

#define H 1024
#define SGS 7
#define BATCH 4096
#define EPS 1e-6f

typedef long long i64;
typedef __attribute__((ext_vector_type(8))) short short8;
typedef __attribute__((ext_vector_type(4))) float f32x4;
typedef __attribute__((ext_vector_type(4))) unsigned int u32x4;

__device__ __forceinline__ unsigned short f2bf(float f) {
  __hip_bfloat16 h = __float2bfloat16(f);   // RNE
  return __builtin_bit_cast(unsigned short, h);
}
__device__ __forceinline__ float b2f(unsigned short u) {
  unsigned int x = ((unsigned int)u) << 16;
  return __builtin_bit_cast(float, x);
}
__device__ __forceinline__ float lo_bf(unsigned int u) {
  return __builtin_bit_cast(float, u << 16);
}
__device__ __forceinline__ float hi_bf(unsigned int u) {
  return __builtin_bit_cast(float, u & 0xFFFF0000u);
}
__device__ __forceinline__ unsigned int pack_bf(float f0, float f1) {
  return (unsigned int)f2bf(f0) | ((unsigned int)f2bf(f1) << 16);
}
__device__ __forceinline__ short8 pack8(float4 a, float4 b) {
  short8 r;
  r[0] = (short)f2bf(a.x); r[1] = (short)f2bf(a.y);
  r[2] = (short)f2bf(a.z); r[3] = (short)f2bf(a.w);
  r[4] = (short)f2bf(b.x); r[5] = (short)f2bf(b.y);
  r[6] = (short)f2bf(b.z); r[7] = (short)f2bf(b.w);
  return r;
}

#define GL16(gp, lp)                                                        \
  __builtin_amdgcn_global_load_lds(                                         \
      (const __attribute__((address_space(1))) unsigned int*)(gp),          \
      (__attribute__((address_space(3))) unsigned int*)(lp), 16, 0, 0)

// Bijective XCD swizzle (m204)
__device__ __forceinline__ void xcd_swz(int& bx, int& by, int& bz) {
  const int gx = gridDim.x, gy = gridDim.y;
  const int nwg = gx * gy * (int)gridDim.z;
  const int orig = blockIdx.x + gx * (blockIdx.y + gy * blockIdx.z);
  const int q = nwg >> 3, r = nwg & 7;
  const int xcd = orig & 7, idx = orig >> 3;
  const int nw = (xcd < r ? xcd * (q + 1) : r * (q + 1) + (xcd - r) * q) + idx;
  bx = nw % gx;
  const int t = nw / gx;
  by = t % gy;
  bz = t / gy;
}

// ============ m97-style GEMM: A[M][K] @ Bt[N][K]^T (+bias)(+relu) ==========
// Tile 128x128, BK in {64,128}, 256 thr (4 waves, 64x64/wave). LDS [128][BK]
// bf16, 16B slots, XOR f(r)=r&7 both-sides. K mult of BK.
template <int ABF16, int OM, int BK>
__global__ __launch_bounds__(256) void ggemm_k(
    const void* __restrict__ Av, int lda, i64 sA,
    const unsigned short* __restrict__ Bt, int ldb, i64 sB,
    float* __restrict__ Cf, unsigned short* __restrict__ Cb, int ldc, i64 sC,
    const float* __restrict__ bias, i64 sBias, int K, int relu)
{
  __shared__ __align__(16) unsigned short As[128 * BK];
  __shared__ __align__(16) unsigned short Bs[128 * BK];

  int bx, by, bz;
  xcd_swz(bx, by, bz);

  const int tid  = threadIdx.x;
  const int lane = tid & 63;
  const int w    = tid >> 6;
  const int wr   = w >> 1, wc = w & 1;   // wave tile rows wr*64, cols wc*64

  const i64 row0 = (i64)by * 128;
  const i64 col0 = (i64)bx * 128;

  const float* Af = (const float*)Av + (i64)bz * sA;
  const unsigned short* Ab = (const unsigned short*)Av + (i64)bz * sA;
  Bt += (i64)bz * sB;
  if (OM & 1) Cf += (i64)bz * sC;
  if (OM & 2) Cb += (i64)bz * sC;
  const float* bi = bias ? bias + (i64)bz * sBias : nullptr;

  // gload staging: wave w stages 32 rows/operand; each GL16 call = 1024B.
  // BK=64: 4 calls x 8 rows; lane -> row lane>>3, slot lane&7, f(r)=r&7
  //        is call-independent: gsl = (lane&7)^(lane>>3).
  // BK=128: 8 calls x 4 rows; lane -> row lane>>4, slot lane&15; f(row) =
  //        (c&1)*4 + (lane>>4) -> two per-lane pointers by call parity.
  const int grA = (BK == 64) ? (lane >> 3) : (lane >> 4);
  const i64 aRow0 = row0 + w * 32 + grA;
  const i64 bRow0 = col0 + w * 32 + grA;
  int gslE, gslO = 0;
  if constexpr (BK == 64) {
    gslE = (lane & 7) ^ grA;
  } else {
    gslE = (lane & 15) ^ grA;
    gslO = (lane & 15) ^ (grA + 4);
  }
  const unsigned short* ApE = Ab + aRow0 * (i64)lda + gslE * 8;
  const unsigned short* ApO = Ab + aRow0 * (i64)lda + gslO * 8;
  const unsigned short* BpE = Bt + bRow0 * (i64)ldb + gslE * 8;
  const unsigned short* BpO = Bt + bRow0 * (i64)ldb + gslO * 8;
  unsigned short* AlB = &As[(w * 32) * BK];
  unsigned short* BlB = &Bs[(w * 32) * BK];

  // fp32-A staging (BK=64 only; never instantiated with BK=128)
  const int arow = tid >> 1, ak0 = (tid & 1) * 4;
  const float* ApF = Af + (row0 + arow) * (i64)lda + ak0 * 8;

  f32x4 acc[4][4];
#pragma unroll
  for (int i = 0; i < 4; ++i)
#pragma unroll
    for (int j = 0; j < 4; ++j) acc[i][j] = (f32x4){0.f, 0.f, 0.f, 0.f};

  const int kq = lane >> 4, lr = lane & 15;
  const int rsw = lr & 7;                  // read-side row XOR

  for (int k0 = 0; k0 < K; k0 += BK) {
    float4 fa[8];
    if constexpr (!ABF16) {   // load before barrier (overlaps prev MFMA)
#pragma unroll
      for (int j = 0; j < 8; ++j) fa[j] = *(const float4*)(ApF + k0 + j * 4);
    }
    __syncthreads();  // prior frag reads done before overwrite
    if constexpr (ABF16) {
      if constexpr (BK == 64) {
#pragma unroll
        for (int c = 0; c < 4; ++c)
          GL16(ApE + k0 + (i64)(c * 8) * lda, AlB + c * 8 * BK);
      } else {
#pragma unroll
        for (int c = 0; c < 8; ++c)
          GL16((c & 1 ? ApO : ApE) + k0 + (i64)(c * 4) * lda, AlB + c * 4 * BK);
      }
    } else {
#pragma unroll
      for (int j = 0; j < 4; ++j)
        *(short8*)(void*)&As[arow * 64 + (((ak0 + j) ^ (arow & 7)) << 3)] =
            pack8(fa[2 * j], fa[2 * j + 1]);
    }
    if constexpr (BK == 64) {
#pragma unroll
      for (int c = 0; c < 4; ++c)
        GL16(BpE + k0 + (i64)(c * 8) * ldb, BlB + c * 8 * BK);
    } else {
#pragma unroll
      for (int c = 0; c < 8; ++c)
        GL16((c & 1 ? BpO : BpE) + k0 + (i64)(c * 4) * ldb, BlB + c * 4 * BK);
    }
    __syncthreads();  // compiler drains vmcnt/lgkm before barrier

#pragma unroll
    for (int h = 0; h < BK / 32; ++h) {    // 32-k halves, in k order
      const int sl = (h * 4 + kq) ^ rsw;
      short8 af[4], bf[4];
#pragma unroll
      for (int mf = 0; mf < 4; ++mf) {
        const int R = wr * 64 + mf * 16 + lr;
        af[mf] = *(const short8*)(const void*)&As[R * BK + (sl << 3)];
      }
#pragma unroll
      for (int nf = 0; nf < 4; ++nf) {
        const int R = wc * 64 + nf * 16 + lr;
        bf[nf] = *(const short8*)(const void*)&Bs[R * BK + (sl << 3)];
      }
#pragma unroll
      for (int mf = 0; mf < 4; ++mf)
#pragma unroll
        for (int nf = 0; nf < 4; ++nf)
          acc[mf][nf] = __builtin_amdgcn_mfma_f32_16x16x32_bf16(
              af[mf], bf[nf], acc[mf][nf], 0, 0, 0);
    }
  }

  // epilogue: D col = lane&15, row = (lane>>4)*4 + reg  [verified r2-r13]
  const int cl = lane & 15, rg = lane >> 4;
#pragma unroll
  for (int nf = 0; nf < 4; ++nf) {
    const i64 col = col0 + wc * 64 + nf * 16 + cl;
    const float bv = bi ? bi[col] : 0.f;
#pragma unroll
    for (int mf = 0; mf < 4; ++mf) {
#pragma unroll
      for (int r = 0; r < 4; ++r) {
        const i64 row = row0 + wr * 64 + mf * 16 + rg * 4 + r;
        float v = acc[mf][nf][r] + bv;
        if (relu) v = fmaxf(v, 0.f);
        if (OM & 1) Cf[row * (i64)ldc + col] = v;
        if (OM & 2) Cb[row * (i64)ldc + col] = f2bf(v);
      }
    }
  }
}

// ---------- fp32 -> bf16 streaming convert (8 elems/thread) ----------------
__global__ __launch_bounds__(256) void f2b_k(
    const float* __restrict__ x, unsigned short* __restrict__ y, i64 n)
{
  const i64 i = ((i64)blockIdx.x * 256 + threadIdx.x) * 8;
  if (i + 8 <= n) {
    float4 a = *(const float4*)(x + i);
    float4 b = *(const float4*)(x + i + 4);
    *(short8*)(void*)(y + i) = pack8(a, b);
  }
}

// ---------- weight transpose+convert: in[K][N] fp32 -> out[N][K] bf16 ------
__global__ __launch_bounds__(256) void wtrans_k(
    const float* __restrict__ in, unsigned short* __restrict__ out,
    int Kd, int Nd, i64 sIn, i64 sOut)
{
  __shared__ float t[32][33];
  in  += (i64)blockIdx.z * sIn;
  out += (i64)blockIdx.z * sOut;
  const int n0 = blockIdx.x * 32, k0 = blockIdx.y * 32;
  const int tx = threadIdx.x & 31, ty = threadIdx.x >> 5;
#pragma unroll
  for (int i = 0; i < 4; ++i)
    t[ty + 8 * i][tx] = in[(i64)(k0 + ty + 8 * i) * Nd + n0 + tx];
  __syncthreads();
#pragma unroll
  for (int i = 0; i < 4; ++i)
    out[(i64)(n0 + ty + 8 * i) * Kd + k0 + tx] = f2bf(t[tx][ty + 8 * i]);
}

// ---- fused LayerNorm + exact GELU + orthonormalization: WAVE per row ------
// V packed 2xbf16 throughout (56 VGPR); LN stats via one interleaved chain;
// current GS row unpacked to fp32 during its step. No forced launch bounds
// (R10 lesson). In-place safe: wave owns its row block.
__global__ __launch_bounds__(256) void lngs2_k(
    const unsigned short* __restrict__ X, const float* __restrict__ gamma,
    const float* __restrict__ beta, unsigned short* __restrict__ Hb)
{
  const int wv = threadIdx.x >> 6, l = threadIdx.x & 63;
  const i64 b = (i64)blockIdx.x * 4 + wv;
  const unsigned short* xr = X + b * (i64)(SGS * H);

  unsigned int Vp[SGS][8];
  float s1[SGS], s2[SGS];
#pragma unroll
  for (int s = 0; s < SGS; ++s) {
    u32x4 a = *(const u32x4*)(const void*)(xr + (i64)s * H + l * 16);
    u32x4 c = *(const u32x4*)(const void*)(xr + (i64)s * H + l * 16 + 8);
    Vp[s][0] = a[0]; Vp[s][1] = a[1]; Vp[s][2] = a[2]; Vp[s][3] = a[3];
    Vp[s][4] = c[0]; Vp[s][5] = c[1]; Vp[s][6] = c[2]; Vp[s][7] = c[3];
    s1[s] = 0.f; s2[s] = 0.f;
#pragma unroll
    for (int q = 0; q < 8; ++q) {
      float f0 = lo_bf(Vp[s][q]), f1 = hi_bf(Vp[s][q]);
      s1[s] += f0 + f1; s2[s] += f0 * f0 + f1 * f1;
    }
  }
  // one 6-step chain, 14 values interleaved
#pragma unroll
  for (int o = 1; o < 64; o <<= 1) {
#pragma unroll
    for (int s = 0; s < SGS; ++s) {
      s1[s] += __shfl_xor(s1[s], o);
      s2[s] += __shfl_xor(s2[s], o);
    }
  }
  // LN + exact GELU, repack (gamma/beta streamed from L1)
#pragma unroll
  for (int s = 0; s < SGS; ++s) {
    const float mu = s1[s] * (1.f / H);
    const float var = s2[s] * (1.f / H) - mu * mu;
    const float rstd = rsqrtf(var + 1e-5f);
#pragma unroll
    for (int q = 0; q < 8; ++q) {
      float2 gv = *(const float2*)(gamma + l * 16 + q * 2);
      float2 bv = *(const float2*)(beta + l * 16 + q * 2);
      float f0 = (lo_bf(Vp[s][q]) - mu) * rstd * gv.x + bv.x;
      float f1 = (hi_bf(Vp[s][q]) - mu) * rstd * gv.y + bv.y;
      f0 = 0.5f * f0 * (1.f + erff(f0 * 0.70710678118654752f));
      f1 = 0.5f * f1 * (1.f + erff(f1 * 0.70710678118654752f));
      Vp[s][q] = pack_bf(f0, f1);
    }
  }

  // orthonormalization: CGS dot-batched; finalized q_j stay packed bf16.
  float dd[SGS];
#pragma unroll
  for (int i = 0; i < SGS; ++i) {
    float f[16];
#pragma unroll
    for (int q = 0; q < 8; ++q) {
      f[2 * q] = lo_bf(Vp[i][q]);
      f[2 * q + 1] = hi_bf(Vp[i][q]);
    }
    if (i > 0) {
      float cc[SGS > 1 ? SGS - 1 : 1];
#pragma unroll
      for (int j = 0; j < i; ++j) {
        cc[j] = 0.f;
#pragma unroll
        for (int q = 0; q < 8; ++q)
          cc[j] += f[2 * q] * lo_bf(Vp[j][q]) + f[2 * q + 1] * hi_bf(Vp[j][q]);
      }
#pragma unroll
      for (int o = 1; o < 64; o <<= 1)
#pragma unroll
        for (int j = 0; j < i; ++j) cc[j] += __shfl_xor(cc[j], o);
#pragma unroll
      for (int j = 0; j < i; ++j) {
        const float proj = (sqrtf(dd[j]) > EPS) ? cc[j] / dd[j] : 0.f;
#pragma unroll
        for (int q = 0; q < 8; ++q) {
          f[2 * q] -= proj * lo_bf(Vp[j][q]);
          f[2 * q + 1] -= proj * hi_bf(Vp[j][q]);
        }
      }
    }
    float nn = 0.f;
#pragma unroll
    for (int e = 0; e < 16; ++e) nn += f[e] * f[e];
#pragma unroll
    for (int o = 1; o < 64; o <<= 1) nn += __shfl_xor(nn, o);
    const float n = sqrtf(nn);
    if (n > EPS) {   // fallback branch statistically unreachable here
      const float inv = 1.f / n;
#pragma unroll
      for (int e = 0; e < 16; ++e) f[e] *= inv;
      dd[i] = nn * inv * inv;    // == dot(q_i,q_i) to ~1e-7
    } else {
      dd[i] = 1.f;
    }
#pragma unroll
    for (int q = 0; q < 8; ++q) Vp[i][q] = pack_bf(f[2 * q], f[2 * q + 1]);
  }

  unsigned short* hr = Hb + b * (i64)(SGS * H) + l * 16;
#pragma unroll
  for (int s = 0; s < SGS; ++s) {
    u32x4 a, c;
    a[0] = Vp[s][0]; a[1] = Vp[s][1]; a[2] = Vp[s][2]; a[3] = Vp[s][3];
    c[0] = Vp[s][4]; c[1] = Vp[s][5]; c[2] = Vp[s][6]; c[3] = Vp[s][7];
    *(u32x4*)(void*)(hr + (i64)s * H) = a;
    *(u32x4*)(void*)(hr + (i64)s * H + 8) = c;
  }
}

__device__ __forceinline__ float block_red(float v, float* scr) {
#pragma unroll
  for (int o = 32; o; o >>= 1) v += __shfl_down(v, o);
  int w = threadIdx.x >> 6;
  if ((threadIdx.x & 63) == 0) scr[w] = v;
  __syncthreads();
  v = scr[0] + scr[1] + scr[2] + scr[3];
  __syncthreads();
  return v;
}

// --------- loss: sum((p-h)^2), p bf16, h bf16 ------------------------------
__global__ __launch_bounds__(256) void loss_part_k(
    const unsigned short* __restrict__ p, const unsigned short* __restrict__ hb,
    float* __restrict__ part)
{
  __shared__ float scr[8];
  const i64 b = blockIdx.x;
  const int s = blockIdx.y;
  const i64 base = b * (i64)(SGS * H) + (i64)s * H;
  const int e = threadIdx.x * 4;
  ushort4 pv = *(const ushort4*)(p + base + e);
  ushort4 hv = *(const ushort4*)(hb + base + e);
  float d0 = b2f(pv.x) - b2f(hv.x), d1 = b2f(pv.y) - b2f(hv.y);
  float d2 = b2f(pv.z) - b2f(hv.z), d3 = b2f(pv.w) - b2f(hv.w);
  float acc = d0 * d0 + d1 * d1 + d2 * d2 + d3 * d3;
  acc = block_red(acc, scr);
  if (threadIdx.x == 0) part[(i64)s * BATCH + b] = acc;
}

__global__ __launch_bounds__(256) void loss_red_k(
    const float* __restrict__ part, float* __restrict__ losses)
{
  __shared__ float scr[8];
  const int s = blockIdx.x;
  float acc = 0.f;
  for (int e = threadIdx.x; e < BATCH; e += 256) acc += part[(i64)s * BATCH + e];
  acc = block_red(acc, scr);
  if (threadIdx.x == 0) losses[s] = acc / (float)((i64)BATCH * H);
}

__global__ void finalize_k(const float* __restrict__ losses,
                           const float* __restrict__ w, float* __restrict__ o)
{
  if (threadIdx.x == 0) {
    float t = 0.f;
#pragma unroll
    for (int s = 0; s < SGS; ++s) { float l = losses[s]; o[1 + s] = l; t += w[s] * l; }
    o[0] = t;
  }
}

// ---------------------------------------------------------------------------
extern "C" void kernel_launch(void* const* d_in, const int* in_sizes, int n_in,
                              void* d_out, int out_size, void* d_ws, size_t ws_size,
                              hipStream_t stream)
{
  (void)in_sizes; (void)n_in; (void)out_size;
  const float* sent    = (const float*)d_in[0];
  const float* decompW = (const float*)d_in[1];
  const float* ln_g    = (const float*)d_in[2];
  const float* ln_b    = (const float*)d_in[3];
  const float* pw1     = (const float*)d_in[4];
  const float* pb1     = (const float*)d_in[5];
  const float* pw2     = (const float*)d_in[6];
  const float* pb2     = (const float*)d_in[7];
  const float* qw1     = (const float*)d_in[8];
  const float* qb1     = (const float*)d_in[9];
  const float* qw2     = (const float*)d_in[10];
  const float* qb2     = (const float*)d_in[11];
  const float* fw1     = (const float*)d_in[12];
  const float* fb1     = (const float*)d_in[13];
  const float* fw2     = (const float*)d_in[14];
  const float* fb2     = (const float*)d_in[15];
  const float* semw    = (const float*)d_in[16];
  float* out = (float*)d_out;

  float* ws = (float*)d_ws;
  const dim3 blk(256);
  const i64 HH = (i64)H * H;
  const i64 SH = (i64)SGS * H;
  const i64 SLABf = (i64)BATCH * SGS * H / 2;      // 14,680,064 fl per bf16 slab

  // full tier needs 3 slabs + W slab + part: 47,738,912 floats = 190.96 MB
  const bool full = ws_size >= (size_t)(3 * SLABf + 3670016 + 28704) * 4;

  if (full) {
    unsigned short* U1 = (unsigned short*)ws;                   // X->H; later fw1t/fw2t/T
    unsigned short* U2 = (unsigned short*)(ws + SLABf);         // sentb -> z1 / p1
    unsigned short* Pb = (unsigned short*)(ws + 2 * SLABf);     // decompWt -> z2 -> p
    unsigned short* W  = (unsigned short*)(ws + 3 * SLABf);     // [7][1024][1024]
    float* part   = ws + 3 * SLABf + 3670016;                   // [7][4096]
    float* losses = part + (i64)SGS * BATCH;
    unsigned short* decompWt = Pb;                              // dies before z2
    unsigned short* sentb = U2;                                 // bf16 sent (dies before z1)
    unsigned short* fw1t = U1;                                  // after H dies
    unsigned short* fw2t = U1 + (i64)2 * H * SGS * H;           // +14,680,064 sh
    unsigned short* T    = fw2t + (i64)H * 2 * H;               // +2,097,152 sh

    // 1) decompWt; sentb = bf16(sent); X = sentb @ decompWt -> U1 (gload path)
    wtrans_k<<<dim3(224, 32, 1), blk, 0, stream>>>(decompW, decompWt, H, SGS * H, 0, 0);
    f2b_k<<<dim3((unsigned)((i64)BATCH * H / 2048)), blk, 0, stream>>>(
        sent, sentb, (i64)BATCH * H);
    ggemm_k<1, 2, 64><<<dim3(56, BATCH / 128, 1), blk, 0, stream>>>(
        sentb, H, 0, decompWt, H, 0, nullptr, U1, SGS * H, 0, nullptr, 0, H, 0);
    // 2) H = GS(gelu(LN(X))) fused, in place
    lngs2_k<<<dim3(BATCH / 4), blk, 0, stream>>>(U1, ln_g, ln_b, U1);
    // 3) SPR stages, full batch (1792 blocks each), one wtrans per weight
    wtrans_k<<<dim3(32, 32, SGS), blk, 0, stream>>>(pw1, W, H, H, HH, HH);
    ggemm_k<1, 2, 64><<<dim3(8, BATCH / 128, SGS), blk, 0, stream>>>(
        U1, SH, H, W, H, HH, nullptr, U2, SH, H, pb1, H, H, 1);  // overwrites sentb (dead)
    wtrans_k<<<dim3(32, 32, SGS), blk, 0, stream>>>(pw2, W, H, H, HH, HH);
    ggemm_k<1, 2, 64><<<dim3(8, BATCH / 128, SGS), blk, 0, stream>>>(
        U2, SH, H, W, H, HH, nullptr, Pb, SH, H, pb2, H, H, 0);  // overwrites decompWt (dead)
    wtrans_k<<<dim3(32, 32, SGS), blk, 0, stream>>>(qw1, W, H, H, HH, HH);
    ggemm_k<1, 2, 64><<<dim3(8, BATCH / 128, SGS), blk, 0, stream>>>(
        Pb, SH, H, W, H, HH, nullptr, U2, SH, H, qb1, H, H, 1);
    wtrans_k<<<dim3(32, 32, SGS), blk, 0, stream>>>(qw2, W, H, H, HH, HH);
    ggemm_k<1, 2, 64><<<dim3(8, BATCH / 128, SGS), blk, 0, stream>>>(
        U2, SH, H, W, H, HH, nullptr, Pb, SH, H, qb2, H, H, 0);  // p -> Pb (z2 dead)
    // 4) loss (p in Pb vs H in U1)
    loss_part_k<<<dim3(BATCH, SGS), blk, 0, stream>>>(Pb, U1, part);
    // 5) fusion: H dead -> fw1t/fw2t/T into U1; BK=128 (low-occupancy GEMMs)
    wtrans_k<<<dim3(64, 224, 1), blk, 0, stream>>>(fw1, fw1t, SGS * H, 2 * H, 0, 0);
    wtrans_k<<<dim3(32, 64, 1), blk, 0, stream>>>(fw2, fw2t, 2 * H, H, 0, 0);
    ggemm_k<1, 2, 128><<<dim3(16, BATCH / 128, 1), blk, 0, stream>>>(
        Pb, SH, 0, fw1t, SGS * H, 0, nullptr, T, 2 * H, 0, fb1, 0, SGS * H, 1);
    ggemm_k<1, 1, 128><<<dim3(8, BATCH / 128, 1), blk, 0, stream>>>(
        T, 2 * H, 0, fw2t, 2 * H, 0, out, nullptr, H, 0, fb2, 0, 2 * H, 0);
    loss_red_k<<<dim3(SGS), blk, 0, stream>>>(part, losses);
    finalize_k<<<dim3(1), dim3(64), 0, stream>>>(losses, semw, out + (i64)BATCH * H);
    return;
  }

  // -------- fallback: proven R7 layout (180.47MB), swizzled --------
  const int BC = 2048;
  unsigned short* W        = (unsigned short*)(ws);             // [7][1024][1024] (reused)
  unsigned short* decompWt = (unsigned short*)(ws + 3670016);   // [7168][1024]
  unsigned short* fw1t     = (unsigned short*)(ws + 7340032);   // [2048][7168]
  unsigned short* fw2t     = (unsigned short*)(ws + 14680064);  // [1024][2048]
  unsigned short* XH       = (unsigned short*)(ws + 15728640);  // chunk [2048][7168]
  unsigned short* Y        = (unsigned short*)(ws + 23068672);  // chunk [2048][7168]
  unsigned short* Pb       = (unsigned short*)(ws + 30408704);  // FULL [4096][7168]
  float* part   = ws + 45088768;                                // [7][4096]
  float* losses = part + (i64)SGS * BATCH;
  unsigned short* T = Y;

  wtrans_k<<<dim3(224, 32, 1), blk, 0, stream>>>(decompW, decompWt, H, SGS * H, 0, 0);
  wtrans_k<<<dim3(64, 224, 1), blk, 0, stream>>>(fw1, fw1t, SGS * H, 2 * H, 0, 0);
  wtrans_k<<<dim3(32, 64, 1), blk, 0, stream>>>(fw2, fw2t, 2 * H, H, 0, 0);

  for (int c = 0; c < BATCH / BC; ++c) {
    const i64 r0 = (i64)c * BC;
    unsigned short* Pc = Pb + r0 * SH;
    ggemm_k<0, 2, 64><<<dim3(56, BC / 128, 1), blk, 0, stream>>>(
        sent + r0 * H, H, 0, decompWt, H, 0, nullptr, XH, SGS * H, 0,
        nullptr, 0, H, 0);
    lngs2_k<<<dim3(BC / 4), blk, 0, stream>>>(XH, ln_g, ln_b, XH);
    wtrans_k<<<dim3(32, 32, SGS), blk, 0, stream>>>(pw1, W, H, H, HH, HH);
    ggemm_k<1, 2, 64><<<dim3(8, BC / 128, SGS), blk, 0, stream>>>(
        XH, SH, H, W, H, HH, nullptr, Y, SH, H, pb1, H, H, 1);
    wtrans_k<<<dim3(32, 32, SGS), blk, 0, stream>>>(pw2, W, H, H, HH, HH);
    ggemm_k<1, 2, 64><<<dim3(8, BC / 128, SGS), blk, 0, stream>>>(
        Y, SH, H, W, H, HH, nullptr, Pc, SH, H, pb2, H, H, 0);
    wtrans_k<<<dim3(32, 32, SGS), blk, 0, stream>>>(qw1, W, H, H, HH, HH);
    ggemm_k<1, 2, 64><<<dim3(8, BC / 128, SGS), blk, 0, stream>>>(
        Pc, SH, H, W, H, HH, nullptr, Y, SH, H, qb1, H, H, 1);
    wtrans_k<<<dim3(32, 32, SGS), blk, 0, stream>>>(qw2, W, H, H, HH, HH);
    ggemm_k<1, 2, 64><<<dim3(8, BC / 128, SGS), blk, 0, stream>>>(
        Y, SH, H, W, H, HH, nullptr, Pc, SH, H, qb2, H, H, 0);
    loss_part_k<<<dim3(BC, SGS), blk, 0, stream>>>(Pc, XH, part + r0);
  }

  ggemm_k<1, 2, 128><<<dim3(16, BATCH / 128, 1), blk, 0, stream>>>(
      Pb, SH, 0, fw1t, SGS * H, 0, nullptr, T, 2 * H, 0, fb1, 0, SGS * H, 1);
  ggemm_k<1, 1, 128><<<dim3(8, BATCH / 128, 1), blk, 0, stream>>>(
      T, 2 * H, 0, fw2t, 2 * H, 0, out, nullptr, H, 0, fb2, 0, 2 * H, 0);

  loss_red_k<<<dim3(SGS), blk, 0, stream>>>(part, losses);
  finalize_k<<<dim3(1), dim3(64), 0, stream>>>(losses, semw, out + (i64)BATCH * H);
}

// Round 16
// 700.240 us; speedup vs baseline: 1.2769x; 1.2769x over previous
//
#include <hip/hip_runtime.h>
#include <hip/hip_bf16.h>

// MultiSemanticSPR: B=4096, H=1024, S=7
// Round 15: revert R14's lngs2 fusion (208 VGPR -> 2 waves/SIMD -> 237us,
// +166us regression; the saved 117MB round-trip was worth only ~20us).
// Restore R13's split ln_gelu_k (~40 VGPR) + gs_k (~100 VGPR). KEEP the
// BK template with BK=128 on fusion1/fusion2 so this round's profile
// A/B-tests it against R13's 153us BK=64 fusion1.

#define H 1024
#define SGS 7
#define BATCH 4096
#define EPS 1e-6f

typedef long long i64;
typedef __attribute__((ext_vector_type(8))) short short8;
typedef __attribute__((ext_vector_type(4))) float f32x4;
typedef __attribute__((ext_vector_type(4))) unsigned int u32x4;

__device__ __forceinline__ unsigned short f2bf(float f) {
  __hip_bfloat16 h = __float2bfloat16(f);   // RNE
  return __builtin_bit_cast(unsigned short, h);
}
__device__ __forceinline__ float b2f(unsigned short u) {
  unsigned int x = ((unsigned int)u) << 16;
  return __builtin_bit_cast(float, x);
}
__device__ __forceinline__ float lo_bf(unsigned int u) {
  return __builtin_bit_cast(float, u << 16);
}
__device__ __forceinline__ float hi_bf(unsigned int u) {
  return __builtin_bit_cast(float, u & 0xFFFF0000u);
}
__device__ __forceinline__ unsigned int pack_bf(float f0, float f1) {
  return (unsigned int)f2bf(f0) | ((unsigned int)f2bf(f1) << 16);
}
__device__ __forceinline__ short8 pack8(float4 a, float4 b) {
  short8 r;
  r[0] = (short)f2bf(a.x); r[1] = (short)f2bf(a.y);
  r[2] = (short)f2bf(a.z); r[3] = (short)f2bf(a.w);
  r[4] = (short)f2bf(b.x); r[5] = (short)f2bf(b.y);
  r[6] = (short)f2bf(b.z); r[7] = (short)f2bf(b.w);
  return r;
}

#define GL16(gp, lp)                                                        \
  __builtin_amdgcn_global_load_lds(                                         \
      (const __attribute__((address_space(1))) unsigned int*)(gp),          \
      (__attribute__((address_space(3))) unsigned int*)(lp), 16, 0, 0)

// Bijective XCD swizzle (m204)
__device__ __forceinline__ void xcd_swz(int& bx, int& by, int& bz) {
  const int gx = gridDim.x, gy = gridDim.y;
  const int nwg = gx * gy * (int)gridDim.z;
  const int orig = blockIdx.x + gx * (blockIdx.y + gy * blockIdx.z);
  const int q = nwg >> 3, r = nwg & 7;
  const int xcd = orig & 7, idx = orig >> 3;
  const int nw = (xcd < r ? xcd * (q + 1) : r * (q + 1) + (xcd - r) * q) + idx;
  bx = nw % gx;
  const int t = nw / gx;
  by = t % gy;
  bz = t / gy;
}

// ============ m97-style GEMM: A[M][K] @ Bt[N][K]^T (+bias)(+relu) ==========
// Tile 128x128, BK in {64,128}, 256 thr (4 waves, 64x64/wave). LDS [128][BK]
// bf16, 16B slots, XOR f(r)=r&7 both-sides. K mult of BK.
template <int ABF16, int OM, int BK>
__global__ __launch_bounds__(256) void ggemm_k(
    const void* __restrict__ Av, int lda, i64 sA,
    const unsigned short* __restrict__ Bt, int ldb, i64 sB,
    float* __restrict__ Cf, unsigned short* __restrict__ Cb, int ldc, i64 sC,
    const float* __restrict__ bias, i64 sBias, int K, int relu)
{
  __shared__ __align__(16) unsigned short As[128 * BK];
  __shared__ __align__(16) unsigned short Bs[128 * BK];

  int bx, by, bz;
  xcd_swz(bx, by, bz);

  const int tid  = threadIdx.x;
  const int lane = tid & 63;
  const int w    = tid >> 6;
  const int wr   = w >> 1, wc = w & 1;   // wave tile rows wr*64, cols wc*64

  const i64 row0 = (i64)by * 128;
  const i64 col0 = (i64)bx * 128;

  const float* Af = (const float*)Av + (i64)bz * sA;
  const unsigned short* Ab = (const unsigned short*)Av + (i64)bz * sA;
  Bt += (i64)bz * sB;
  if (OM & 1) Cf += (i64)bz * sC;
  if (OM & 2) Cb += (i64)bz * sC;
  const float* bi = bias ? bias + (i64)bz * sBias : nullptr;

  // gload staging: wave w stages 32 rows/operand; each GL16 call = 1024B.
  // BK=64: 4 calls x 8 rows; gsl = (lane&7)^(lane>>3) (call-independent).
  // BK=128: 8 calls x 4 rows; f(row) alternates by call parity -> 2 ptrs.
  const int grA = (BK == 64) ? (lane >> 3) : (lane >> 4);
  const i64 aRow0 = row0 + w * 32 + grA;
  const i64 bRow0 = col0 + w * 32 + grA;
  int gslE, gslO = 0;
  if constexpr (BK == 64) {
    gslE = (lane & 7) ^ grA;
  } else {
    gslE = (lane & 15) ^ grA;
    gslO = (lane & 15) ^ (grA + 4);
  }
  const unsigned short* ApE = Ab + aRow0 * (i64)lda + gslE * 8;
  const unsigned short* ApO = Ab + aRow0 * (i64)lda + gslO * 8;
  const unsigned short* BpE = Bt + bRow0 * (i64)ldb + gslE * 8;
  const unsigned short* BpO = Bt + bRow0 * (i64)ldb + gslO * 8;
  unsigned short* AlB = &As[(w * 32) * BK];
  unsigned short* BlB = &Bs[(w * 32) * BK];

  // fp32-A staging (BK=64 only; never instantiated with BK=128)
  const int arow = tid >> 1, ak0 = (tid & 1) * 4;
  const float* ApF = Af + (row0 + arow) * (i64)lda + ak0 * 8;

  f32x4 acc[4][4];
#pragma unroll
  for (int i = 0; i < 4; ++i)
#pragma unroll
    for (int j = 0; j < 4; ++j) acc[i][j] = (f32x4){0.f, 0.f, 0.f, 0.f};

  const int kq = lane >> 4, lr = lane & 15;
  const int rsw = lr & 7;                  // read-side row XOR

  for (int k0 = 0; k0 < K; k0 += BK) {
    float4 fa[8];
    if constexpr (!ABF16) {   // load before barrier (overlaps prev MFMA)
#pragma unroll
      for (int j = 0; j < 8; ++j) fa[j] = *(const float4*)(ApF + k0 + j * 4);
    }
    __syncthreads();  // prior frag reads done before overwrite
    if constexpr (ABF16) {
      if constexpr (BK == 64) {
#pragma unroll
        for (int c = 0; c < 4; ++c)
          GL16(ApE + k0 + (i64)(c * 8) * lda, AlB + c * 8 * BK);
      } else {
#pragma unroll
        for (int c = 0; c < 8; ++c)
          GL16((c & 1 ? ApO : ApE) + k0 + (i64)(c * 4) * lda, AlB + c * 4 * BK);
      }
    } else {
#pragma unroll
      for (int j = 0; j < 4; ++j)
        *(short8*)(void*)&As[arow * 64 + (((ak0 + j) ^ (arow & 7)) << 3)] =
            pack8(fa[2 * j], fa[2 * j + 1]);
    }
    if constexpr (BK == 64) {
#pragma unroll
      for (int c = 0; c < 4; ++c)
        GL16(BpE + k0 + (i64)(c * 8) * ldb, BlB + c * 8 * BK);
    } else {
#pragma unroll
      for (int c = 0; c < 8; ++c)
        GL16((c & 1 ? BpO : BpE) + k0 + (i64)(c * 4) * ldb, BlB + c * 4 * BK);
    }
    __syncthreads();  // compiler drains vmcnt/lgkm before barrier

#pragma unroll
    for (int h = 0; h < BK / 32; ++h) {    // 32-k halves, in k order
      const int sl = (h * 4 + kq) ^ rsw;
      short8 af[4], bf[4];
#pragma unroll
      for (int mf = 0; mf < 4; ++mf) {
        const int R = wr * 64 + mf * 16 + lr;
        af[mf] = *(const short8*)(const void*)&As[R * BK + (sl << 3)];
      }
#pragma unroll
      for (int nf = 0; nf < 4; ++nf) {
        const int R = wc * 64 + nf * 16 + lr;
        bf[nf] = *(const short8*)(const void*)&Bs[R * BK + (sl << 3)];
      }
#pragma unroll
      for (int mf = 0; mf < 4; ++mf)
#pragma unroll
        for (int nf = 0; nf < 4; ++nf)
          acc[mf][nf] = __builtin_amdgcn_mfma_f32_16x16x32_bf16(
              af[mf], bf[nf], acc[mf][nf], 0, 0, 0);
    }
  }

  // epilogue: D col = lane&15, row = (lane>>4)*4 + reg  [verified r2-r14]
  const int cl = lane & 15, rg = lane >> 4;
#pragma unroll
  for (int nf = 0; nf < 4; ++nf) {
    const i64 col = col0 + wc * 64 + nf * 16 + cl;
    const float bv = bi ? bi[col] : 0.f;
#pragma unroll
    for (int mf = 0; mf < 4; ++mf) {
#pragma unroll
      for (int r = 0; r < 4; ++r) {
        const i64 row = row0 + wr * 64 + mf * 16 + rg * 4 + r;
        float v = acc[mf][nf][r] + bv;
        if (relu) v = fmaxf(v, 0.f);
        if (OM & 1) Cf[row * (i64)ldc + col] = v;
        if (OM & 2) Cb[row * (i64)ldc + col] = f2bf(v);
      }
    }
  }
}

// ---------- fp32 -> bf16 streaming convert (8 elems/thread) ----------------
__global__ __launch_bounds__(256) void f2b_k(
    const float* __restrict__ x, unsigned short* __restrict__ y, i64 n)
{
  const i64 i = ((i64)blockIdx.x * 256 + threadIdx.x) * 8;
  if (i + 8 <= n) {
    float4 a = *(const float4*)(x + i);
    float4 b = *(const float4*)(x + i + 4);
    *(short8*)(void*)(y + i) = pack8(a, b);
  }
}

// ---------- weight transpose+convert: in[K][N] fp32 -> out[N][K] bf16 ------
__global__ __launch_bounds__(256) void wtrans_k(
    const float* __restrict__ in, unsigned short* __restrict__ out,
    int Kd, int Nd, i64 sIn, i64 sOut)
{
  __shared__ float t[32][33];
  in  += (i64)blockIdx.z * sIn;
  out += (i64)blockIdx.z * sOut;
  const int n0 = blockIdx.x * 32, k0 = blockIdx.y * 32;
  const int tx = threadIdx.x & 31, ty = threadIdx.x >> 5;
#pragma unroll
  for (int i = 0; i < 4; ++i)
    t[ty + 8 * i][tx] = in[(i64)(k0 + ty + 8 * i) * Nd + n0 + tx];
  __syncthreads();
#pragma unroll
  for (int i = 0; i < 4; ++i)
    out[(i64)(n0 + ty + 8 * i) * Kd + k0 + tx] = f2bf(t[tx][ty + 8 * i]);
}

// ---------- LayerNorm + exact GELU: one WAVE per (b,s) row, streaming ------
// ~40 VGPR, high occupancy. In-place safe (wave owns its row).
__global__ __launch_bounds__(256) void ln_gelu_k(
    const unsigned short* __restrict__ X, const float* __restrict__ gamma,
    const float* __restrict__ beta, unsigned short* __restrict__ Y)
{
  const int wv = threadIdx.x >> 6, l = threadIdx.x & 63;
  const i64 row = (i64)blockIdx.x * 4 + wv;       // row in [0, BATCH*SGS)
  const unsigned short* xr = X + row * H + l * 16;

  unsigned int Vp[8];
  {
    u32x4 a = *(const u32x4*)(const void*)(xr);
    u32x4 c = *(const u32x4*)(const void*)(xr + 8);
    Vp[0] = a[0]; Vp[1] = a[1]; Vp[2] = a[2]; Vp[3] = a[3];
    Vp[4] = c[0]; Vp[5] = c[1]; Vp[6] = c[2]; Vp[7] = c[3];
  }
  float s1 = 0.f, s2 = 0.f;
#pragma unroll
  for (int q = 0; q < 8; ++q) {
    float f0 = lo_bf(Vp[q]), f1 = hi_bf(Vp[q]);
    s1 += f0 + f1; s2 += f0 * f0 + f1 * f1;
  }
#pragma unroll
  for (int o = 1; o < 64; o <<= 1) {
    s1 += __shfl_xor(s1, o);
    s2 += __shfl_xor(s2, o);
  }
  const float mu = s1 * (1.f / H);
  const float var = s2 * (1.f / H) - mu * mu;
  const float rstd = rsqrtf(var + 1e-5f);
#pragma unroll
  for (int q = 0; q < 8; ++q) {
    float2 gv = *(const float2*)(gamma + l * 16 + q * 2);
    float2 bv = *(const float2*)(beta + l * 16 + q * 2);
    float f0 = (lo_bf(Vp[q]) - mu) * rstd * gv.x + bv.x;
    float f1 = (hi_bf(Vp[q]) - mu) * rstd * gv.y + bv.y;
    f0 = 0.5f * f0 * (1.f + erff(f0 * 0.70710678118654752f));
    f1 = 0.5f * f1 * (1.f + erff(f1 * 0.70710678118654752f));
    Vp[q] = pack_bf(f0, f1);
  }
  unsigned short* yr = Y + row * H + l * 16;
  u32x4 a, c;
  a[0] = Vp[0]; a[1] = Vp[1]; a[2] = Vp[2]; a[3] = Vp[3];
  c[0] = Vp[4]; c[1] = Vp[5]; c[2] = Vp[6]; c[7 - 7] = c[0];
  c[0] = Vp[4]; c[1] = Vp[5]; c[2] = Vp[6]; c[3] = Vp[7];
  *(u32x4*)(void*)(yr) = a;
  *(u32x4*)(void*)(yr + 8) = c;
}

// ---------- orthonormalization (CGS dot-batched): one WAVE per batch row ---
// V packed 2xbf16 (56 VGPR); current row fp32 during its step. No forced
// launch bounds (R10/R14 lesson). In-place safe.
__global__ __launch_bounds__(256) void gs_k(
    const unsigned short* __restrict__ X, unsigned short* __restrict__ Hb)
{
  const int wv = threadIdx.x >> 6, l = threadIdx.x & 63;
  const i64 b = (i64)blockIdx.x * 4 + wv;
  const unsigned short* xr = X + b * (i64)(SGS * H);

  unsigned int Vp[SGS][8];
#pragma unroll
  for (int s = 0; s < SGS; ++s) {
    u32x4 a = *(const u32x4*)(const void*)(xr + (i64)s * H + l * 16);
    u32x4 c = *(const u32x4*)(const void*)(xr + (i64)s * H + l * 16 + 8);
    Vp[s][0] = a[0]; Vp[s][1] = a[1]; Vp[s][2] = a[2]; Vp[s][3] = a[3];
    Vp[s][4] = c[0]; Vp[s][5] = c[1]; Vp[s][6] = c[2]; Vp[s][7] = c[3];
  }

  float dd[SGS];
#pragma unroll
  for (int i = 0; i < SGS; ++i) {
    float f[16];
#pragma unroll
    for (int q = 0; q < 8; ++q) {
      f[2 * q] = lo_bf(Vp[i][q]);
      f[2 * q + 1] = hi_bf(Vp[i][q]);
    }
    if (i > 0) {
      float cc[SGS > 1 ? SGS - 1 : 1];
#pragma unroll
      for (int j = 0; j < i; ++j) {
        cc[j] = 0.f;
#pragma unroll
        for (int q = 0; q < 8; ++q)
          cc[j] += f[2 * q] * lo_bf(Vp[j][q]) + f[2 * q + 1] * hi_bf(Vp[j][q]);
      }
#pragma unroll
      for (int o = 1; o < 64; o <<= 1)
#pragma unroll
        for (int j = 0; j < i; ++j) cc[j] += __shfl_xor(cc[j], o);
#pragma unroll
      for (int j = 0; j < i; ++j) {
        const float proj = (sqrtf(dd[j]) > EPS) ? cc[j] / dd[j] : 0.f;
#pragma unroll
        for (int q = 0; q < 8; ++q) {
          f[2 * q] -= proj * lo_bf(Vp[j][q]);
          f[2 * q + 1] -= proj * hi_bf(Vp[j][q]);
        }
      }
    }
    float nn = 0.f;
#pragma unroll
    for (int e = 0; e < 16; ++e) nn += f[e] * f[e];
#pragma unroll
    for (int o = 1; o < 64; o <<= 1) nn += __shfl_xor(nn, o);
    const float n = sqrtf(nn);
    if (n > EPS) {   // fallback branch statistically unreachable here
      const float inv = 1.f / n;
#pragma unroll
      for (int e = 0; e < 16; ++e) f[e] *= inv;
      dd[i] = nn * inv * inv;    // == dot(q_i,q_i) to ~1e-7
    } else {
      dd[i] = 1.f;
    }
#pragma unroll
    for (int q = 0; q < 8; ++q) Vp[i][q] = pack_bf(f[2 * q], f[2 * q + 1]);
  }

  unsigned short* hr = Hb + b * (i64)(SGS * H) + l * 16;
#pragma unroll
  for (int s = 0; s < SGS; ++s) {
    u32x4 a, c;
    a[0] = Vp[s][0]; a[1] = Vp[s][1]; a[2] = Vp[s][2]; a[3] = Vp[s][3];
    c[0] = Vp[s][4]; c[1] = Vp[s][5]; c[2] = Vp[s][6]; c[3] = Vp[s][7];
    *(u32x4*)(void*)(hr + (i64)s * H) = a;
    *(u32x4*)(void*)(hr + (i64)s * H + 8) = c;
  }
}

__device__ __forceinline__ float block_red(float v, float* scr) {
#pragma unroll
  for (int o = 32; o; o >>= 1) v += __shfl_down(v, o);
  int w = threadIdx.x >> 6;
  if ((threadIdx.x & 63) == 0) scr[w] = v;
  __syncthreads();
  v = scr[0] + scr[1] + scr[2] + scr[3];
  __syncthreads();
  return v;
}

// --------- loss: sum((p-h)^2), p bf16, h bf16 ------------------------------
__global__ __launch_bounds__(256) void loss_part_k(
    const unsigned short* __restrict__ p, const unsigned short* __restrict__ hb,
    float* __restrict__ part)
{
  __shared__ float scr[8];
  const i64 b = blockIdx.x;
  const int s = blockIdx.y;
  const i64 base = b * (i64)(SGS * H) + (i64)s * H;
  const int e = threadIdx.x * 4;
  ushort4 pv = *(const ushort4*)(p + base + e);
  ushort4 hv = *(const ushort4*)(hb + base + e);
  float d0 = b2f(pv.x) - b2f(hv.x), d1 = b2f(pv.y) - b2f(hv.y);
  float d2 = b2f(pv.z) - b2f(hv.z), d3 = b2f(pv.w) - b2f(hv.w);
  float acc = d0 * d0 + d1 * d1 + d2 * d2 + d3 * d3;
  acc = block_red(acc, scr);
  if (threadIdx.x == 0) part[(i64)s * BATCH + b] = acc;
}

__global__ __launch_bounds__(256) void loss_red_k(
    const float* __restrict__ part, float* __restrict__ losses)
{
  __shared__ float scr[8];
  const int s = blockIdx.x;
  float acc = 0.f;
  for (int e = threadIdx.x; e < BATCH; e += 256) acc += part[(i64)s * BATCH + e];
  acc = block_red(acc, scr);
  if (threadIdx.x == 0) losses[s] = acc / (float)((i64)BATCH * H);
}

__global__ void finalize_k(const float* __restrict__ losses,
                           const float* __restrict__ w, float* __restrict__ o)
{
  if (threadIdx.x == 0) {
    float t = 0.f;
#pragma unroll
    for (int s = 0; s < SGS; ++s) { float l = losses[s]; o[1 + s] = l; t += w[s] * l; }
    o[0] = t;
  }
}

// ---------------------------------------------------------------------------
extern "C" void kernel_launch(void* const* d_in, const int* in_sizes, int n_in,
                              void* d_out, int out_size, void* d_ws, size_t ws_size,
                              hipStream_t stream)
{
  (void)in_sizes; (void)n_in; (void)out_size;
  const float* sent    = (const float*)d_in[0];
  const float* decompW = (const float*)d_in[1];
  const float* ln_g    = (const float*)d_in[2];
  const float* ln_b    = (const float*)d_in[3];
  const float* pw1     = (const float*)d_in[4];
  const float* pb1     = (const float*)d_in[5];
  const float* pw2     = (const float*)d_in[6];
  const float* pb2     = (const float*)d_in[7];
  const float* qw1     = (const float*)d_in[8];
  const float* qb1     = (const float*)d_in[9];
  const float* qw2     = (const float*)d_in[10];
  const float* qb2     = (const float*)d_in[11];
  const float* fw1     = (const float*)d_in[12];
  const float* fb1     = (const float*)d_in[13];
  const float* fw2     = (const float*)d_in[14];
  const float* fb2     = (const float*)d_in[15];
  const float* semw    = (const float*)d_in[16];
  float* out = (float*)d_out;

  float* ws = (float*)d_ws;
  const dim3 blk(256);
  const i64 HH = (i64)H * H;
  const i64 SH = (i64)SGS * H;
  const i64 SLABf = (i64)BATCH * SGS * H / 2;      // 14,680,064 fl per bf16 slab

  // full tier needs 3 slabs + W slab + part: 47,738,912 floats = 190.96 MB
  const bool full = ws_size >= (size_t)(3 * SLABf + 3670016 + 28704) * 4;

  if (full) {
    unsigned short* U1 = (unsigned short*)ws;                   // X->H; later fw1t/fw2t/T
    unsigned short* U2 = (unsigned short*)(ws + SLABf);         // sentb -> z1 / p1
    unsigned short* Pb = (unsigned short*)(ws + 2 * SLABf);     // decompWt -> z2 -> p
    unsigned short* W  = (unsigned short*)(ws + 3 * SLABf);     // [7][1024][1024]
    float* part   = ws + 3 * SLABf + 3670016;                   // [7][4096]
    float* losses = part + (i64)SGS * BATCH;
    unsigned short* decompWt = Pb;                              // dies before z2
    unsigned short* sentb = U2;                                 // bf16 sent (dies before z1)
    unsigned short* fw1t = U1;                                  // after H dies
    unsigned short* fw2t = U1 + (i64)2 * H * SGS * H;           // +14,680,064 sh
    unsigned short* T    = fw2t + (i64)H * 2 * H;               // +2,097,152 sh

    // 1) decompWt; sentb = bf16(sent); X = sentb @ decompWt -> U1 (gload path)
    wtrans_k<<<dim3(224, 32, 1), blk, 0, stream>>>(decompW, decompWt, H, SGS * H, 0, 0);
    f2b_k<<<dim3((unsigned)((i64)BATCH * H / 2048)), blk, 0, stream>>>(
        sent, sentb, (i64)BATCH * H);
    ggemm_k<1, 2, 64><<<dim3(56, BATCH / 128, 1), blk, 0, stream>>>(
        sentb, H, 0, decompWt, H, 0, nullptr, U1, SGS * H, 0, nullptr, 0, H, 0);
    // 2) LN+GELU then GS, both in place (split: VGPR discipline, R14 lesson)
    ln_gelu_k<<<dim3(BATCH * SGS / 4), blk, 0, stream>>>(U1, ln_g, ln_b, U1);
    gs_k<<<dim3(BATCH / 4), blk, 0, stream>>>(U1, U1);
    // 3) SPR stages, full batch (1792 blocks each), one wtrans per weight
    wtrans_k<<<dim3(32, 32, SGS), blk, 0, stream>>>(pw1, W, H, H, HH, HH);
    ggemm_k<1, 2, 64><<<dim3(8, BATCH / 128, SGS), blk, 0, stream>>>(
        U1, SH, H, W, H, HH, nullptr, U2, SH, H, pb1, H, H, 1);  // overwrites sentb (dead)
    wtrans_k<<<dim3(32, 32, SGS), blk, 0, stream>>>(pw2, W, H, H, HH, HH);
    ggemm_k<1, 2, 64><<<dim3(8, BATCH / 128, SGS), blk, 0, stream>>>(
        U2, SH, H, W, H, HH, nullptr, Pb, SH, H, pb2, H, H, 0);  // overwrites decompWt (dead)
    wtrans_k<<<dim3(32, 32, SGS), blk, 0, stream>>>(qw1, W, H, H, HH, HH);
    ggemm_k<1, 2, 64><<<dim3(8, BATCH / 128, SGS), blk, 0, stream>>>(
        Pb, SH, H, W, H, HH, nullptr, U2, SH, H, qb1, H, H, 1);
    wtrans_k<<<dim3(32, 32, SGS), blk, 0, stream>>>(qw2, W, H, H, HH, HH);
    ggemm_k<1, 2, 64><<<dim3(8, BATCH / 128, SGS), blk, 0, stream>>>(
        U2, SH, H, W, H, HH, nullptr, Pb, SH, H, qb2, H, H, 0);  // p -> Pb (z2 dead)
    // 4) loss (p in Pb vs H in U1)
    loss_part_k<<<dim3(BATCH, SGS), blk, 0, stream>>>(Pb, U1, part);
    // 5) fusion: H dead -> fw1t/fw2t/T into U1; BK=128 (low-occupancy GEMMs)
    wtrans_k<<<dim3(64, 224, 1), blk, 0, stream>>>(fw1, fw1t, SGS * H, 2 * H, 0, 0);
    wtrans_k<<<dim3(32, 64, 1), blk, 0, stream>>>(fw2, fw2t, 2 * H, H, 0, 0);
    ggemm_k<1, 2, 128><<<dim3(16, BATCH / 128, 1), blk, 0, stream>>>(
        Pb, SH, 0, fw1t, SGS * H, 0, nullptr, T, 2 * H, 0, fb1, 0, SGS * H, 1);
    ggemm_k<1, 1, 128><<<dim3(8, BATCH / 128, 1), blk, 0, stream>>>(
        T, 2 * H, 0, fw2t, 2 * H, 0, out, nullptr, H, 0, fb2, 0, 2 * H, 0);
    loss_red_k<<<dim3(SGS), blk, 0, stream>>>(part, losses);
    finalize_k<<<dim3(1), dim3(64), 0, stream>>>(losses, semw, out + (i64)BATCH * H);
    return;
  }

  // -------- fallback: proven R7 layout (180.47MB), swizzled --------
  const int BC = 2048;
  unsigned short* W        = (unsigned short*)(ws);             // [7][1024][1024] (reused)
  unsigned short* decompWt = (unsigned short*)(ws + 3670016);   // [7168][1024]
  unsigned short* fw1t     = (unsigned short*)(ws + 7340032);   // [2048][7168]
  unsigned short* fw2t     = (unsigned short*)(ws + 14680064);  // [1024][2048]
  unsigned short* XH       = (unsigned short*)(ws + 15728640);  // chunk [2048][7168]
  unsigned short* Y        = (unsigned short*)(ws + 23068672);  // chunk [2048][7168]
  unsigned short* Pb       = (unsigned short*)(ws + 30408704);  // FULL [4096][7168]
  float* part   = ws + 45088768;                                // [7][4096]
  float* losses = part + (i64)SGS * BATCH;
  unsigned short* T = Y;

  wtrans_k<<<dim3(224, 32, 1), blk, 0, stream>>>(decompW, decompWt, H, SGS * H, 0, 0);
  wtrans_k<<<dim3(64, 224, 1), blk, 0, stream>>>(fw1, fw1t, SGS * H, 2 * H, 0, 0);
  wtrans_k<<<dim3(32, 64, 1), blk, 0, stream>>>(fw2, fw2t, 2 * H, H, 0, 0);

  for (int c = 0; c < BATCH / BC; ++c) {
    const i64 r0 = (i64)c * BC;
    unsigned short* Pc = Pb + r0 * SH;
    ggemm_k<0, 2, 64><<<dim3(56, BC / 128, 1), blk, 0, stream>>>(
        sent + r0 * H, H, 0, decompWt, H, 0, nullptr, XH, SGS * H, 0,
        nullptr, 0, H, 0);
    ln_gelu_k<<<dim3(BC * SGS / 4), blk, 0, stream>>>(XH, ln_g, ln_b, XH);
    gs_k<<<dim3(BC / 4), blk, 0, stream>>>(XH, XH);
    wtrans_k<<<dim3(32, 32, SGS), blk, 0, stream>>>(pw1, W, H, H, HH, HH);
    ggemm_k<1, 2, 64><<<dim3(8, BC / 128, SGS), blk, 0, stream>>>(
        XH, SH, H, W, H, HH, nullptr, Y, SH, H, pb1, H, H, 1);
    wtrans_k<<<dim3(32, 32, SGS), blk, 0, stream>>>(pw2, W, H, H, HH, HH);
    ggemm_k<1, 2, 64><<<dim3(8, BC / 128, SGS), blk, 0, stream>>>(
        Y, SH, H, W, H, HH, nullptr, Pc, SH, H, pb2, H, H, 0);
    wtrans_k<<<dim3(32, 32, SGS), blk, 0, stream>>>(qw1, W, H, H, HH, HH);
    ggemm_k<1, 2, 64><<<dim3(8, BC / 128, SGS), blk, 0, stream>>>(
        Pc, SH, H, W, H, HH, nullptr, Y, SH, H, qb1, H, H, 1);
    wtrans_k<<<dim3(32, 32, SGS), blk, 0, stream>>>(qw2, W, H, H, HH, HH);
    ggemm_k<1, 2, 64><<<dim3(8, BC / 128, SGS), blk, 0, stream>>>(
        Y, SH, H, W, H, HH, nullptr, Pc, SH, H, qb2, H, H, 0);
    loss_part_k<<<dim3(BC, SGS), blk, 0, stream>>>(Pc, XH, part + r0);
  }

  ggemm_k<1, 2, 128><<<dim3(16, BATCH / 128, 1), blk, 0, stream>>>(
      Pb, SH, 0, fw1t, SGS * H, 0, nullptr, T, 2 * H, 0, fb1, 0, SGS * H, 1);
  ggemm_k<1, 1, 128><<<dim3(8, BATCH / 128, 1), blk, 0, stream>>>(
      T, 2 * H, 0, fw2t, 2 * H, 0, out, nullptr, H, 0, fb2, 0, 2 * H, 0);

  loss_red_k<<<dim3(SGS), blk, 0, stream>>>(part, losses);
  finalize_k<<<dim3(1), dim3(64), 0, stream>>>(losses, semw, out + (i64)BATCH * H);
}

// Round 17
// 697.580 us; speedup vs baseline: 1.2818x; 1.0038x over previous
//
#include <hip/hip_runtime.h>
#include <hip/hip_bf16.h>

// MultiSemanticSPR: B=4096, H=1024, S=7
// Round 16: BK=128 bank-conflict fix. R15's BK=128 fusion GEMMs showed
// 1.468e7 conflicts (BK=64 = 0): the 3-bit XOR (lr&7) over 16-slot rows
// leaves row-bit-3 unmixed -> ~4-way aliasing. Now f(row)=row&15:
//  write: GL16 call c (4 rows) uses f = 4*(c&3)|grA -> 4 pre-swizzled
//         per-lane pointers (compile-time c&3 index);
//  read:  slot = (h*4+kq) ^ lr   (full 4 bits; frag row base == 0 mod 16).
// Involution both sides -> bit-identical. BK=64 path untouched (proven 0).

#define H 1024
#define SGS 7
#define BATCH 4096
#define EPS 1e-6f

typedef long long i64;
typedef __attribute__((ext_vector_type(8))) short short8;
typedef __attribute__((ext_vector_type(4))) float f32x4;
typedef __attribute__((ext_vector_type(4))) unsigned int u32x4;

__device__ __forceinline__ unsigned short f2bf(float f) {
  __hip_bfloat16 h = __float2bfloat16(f);   // RNE
  return __builtin_bit_cast(unsigned short, h);
}
__device__ __forceinline__ float b2f(unsigned short u) {
  unsigned int x = ((unsigned int)u) << 16;
  return __builtin_bit_cast(float, x);
}
__device__ __forceinline__ float lo_bf(unsigned int u) {
  return __builtin_bit_cast(float, u << 16);
}
__device__ __forceinline__ float hi_bf(unsigned int u) {
  return __builtin_bit_cast(float, u & 0xFFFF0000u);
}
__device__ __forceinline__ unsigned int pack_bf(float f0, float f1) {
  return (unsigned int)f2bf(f0) | ((unsigned int)f2bf(f1) << 16);
}
__device__ __forceinline__ short8 pack8(float4 a, float4 b) {
  short8 r;
  r[0] = (short)f2bf(a.x); r[1] = (short)f2bf(a.y);
  r[2] = (short)f2bf(a.z); r[3] = (short)f2bf(a.w);
  r[4] = (short)f2bf(b.x); r[5] = (short)f2bf(b.y);
  r[6] = (short)f2bf(b.z); r[7] = (short)f2bf(b.w);
  return r;
}

#define GL16(gp, lp)                                                        \
  __builtin_amdgcn_global_load_lds(                                         \
      (const __attribute__((address_space(1))) unsigned int*)(gp),          \
      (__attribute__((address_space(3))) unsigned int*)(lp), 16, 0, 0)

// Bijective XCD swizzle (m204)
__device__ __forceinline__ void xcd_swz(int& bx, int& by, int& bz) {
  const int gx = gridDim.x, gy = gridDim.y;
  const int nwg = gx * gy * (int)gridDim.z;
  const int orig = blockIdx.x + gx * (blockIdx.y + gy * blockIdx.z);
  const int q = nwg >> 3, r = nwg & 7;
  const int xcd = orig & 7, idx = orig >> 3;
  const int nw = (xcd < r ? xcd * (q + 1) : r * (q + 1) + (xcd - r) * q) + idx;
  bx = nw % gx;
  const int t = nw / gx;
  by = t % gy;
  bz = t / gy;
}

// ============ m97-style GEMM: A[M][K] @ Bt[N][K]^T (+bias)(+relu) ==========
// Tile 128x128, BK in {64,128}, 256 thr (4 waves, 64x64/wave). LDS [128][BK]
// bf16, 16B slots. XOR swizzle: BK=64 f(r)=r&7; BK=128 f(r)=r&15. K mult BK.
template <int ABF16, int OM, int BK>
__global__ __launch_bounds__(256) void ggemm_k(
    const void* __restrict__ Av, int lda, i64 sA,
    const unsigned short* __restrict__ Bt, int ldb, i64 sB,
    float* __restrict__ Cf, unsigned short* __restrict__ Cb, int ldc, i64 sC,
    const float* __restrict__ bias, i64 sBias, int K, int relu)
{
  __shared__ __align__(16) unsigned short As[128 * BK];
  __shared__ __align__(16) unsigned short Bs[128 * BK];

  int bx, by, bz;
  xcd_swz(bx, by, bz);

  const int tid  = threadIdx.x;
  const int lane = tid & 63;
  const int w    = tid >> 6;
  const int wr   = w >> 1, wc = w & 1;   // wave tile rows wr*64, cols wc*64

  const i64 row0 = (i64)by * 128;
  const i64 col0 = (i64)bx * 128;

  const float* Af = (const float*)Av + (i64)bz * sA;
  const unsigned short* Ab = (const unsigned short*)Av + (i64)bz * sA;
  Bt += (i64)bz * sB;
  if (OM & 1) Cf += (i64)bz * sC;
  if (OM & 2) Cb += (i64)bz * sC;
  const float* bi = bias ? bias + (i64)bz * sBias : nullptr;

  // gload staging: wave w stages 32 rows/operand; each GL16 call = 1024B.
  // BK=64: 4 calls x 8 rows; f(r)=r&7 call-independent:
  //        gsl = (lane&7)^(lane>>3).
  // BK=128: 8 calls x 4 rows; f(r)=r&15 = 4*(c&3)|grA -> 4 pointer sets.
  const int grA = (BK == 64) ? (lane >> 3) : (lane >> 4);
  const i64 aRow0 = row0 + w * 32 + grA;
  const i64 bRow0 = col0 + w * 32 + grA;
  const unsigned short* Ap4[BK == 64 ? 1 : 4];
  const unsigned short* Bp4[BK == 64 ? 1 : 4];
  if constexpr (BK == 64) {
    const int gsl = (lane & 7) ^ grA;
    Ap4[0] = Ab + aRow0 * (i64)lda + gsl * 8;
    Bp4[0] = Bt + bRow0 * (i64)ldb + gsl * 8;
  } else {
#pragma unroll
    for (int c4 = 0; c4 < 4; ++c4) {
      const int gsl = (lane & 15) ^ ((c4 * 4) | grA);
      Ap4[c4] = Ab + aRow0 * (i64)lda + gsl * 8;
      Bp4[c4] = Bt + bRow0 * (i64)ldb + gsl * 8;
    }
  }
  unsigned short* AlB = &As[(w * 32) * BK];
  unsigned short* BlB = &Bs[(w * 32) * BK];

  // fp32-A staging (BK=64 only; never instantiated with BK=128)
  const int arow = tid >> 1, ak0 = (tid & 1) * 4;
  const float* ApF = Af + (row0 + arow) * (i64)lda + ak0 * 8;

  f32x4 acc[4][4];
#pragma unroll
  for (int i = 0; i < 4; ++i)
#pragma unroll
    for (int j = 0; j < 4; ++j) acc[i][j] = (f32x4){0.f, 0.f, 0.f, 0.f};

  const int kq = lane >> 4, lr = lane & 15;
  const int rsw = (BK == 128) ? lr : (lr & 7);   // read-side row XOR

  for (int k0 = 0; k0 < K; k0 += BK) {
    float4 fa[8];
    if constexpr (!ABF16) {   // load before barrier (overlaps prev MFMA)
#pragma unroll
      for (int j = 0; j < 8; ++j) fa[j] = *(const float4*)(ApF + k0 + j * 4);
    }
    __syncthreads();  // prior frag reads done before overwrite
    if constexpr (ABF16) {
      if constexpr (BK == 64) {
#pragma unroll
        for (int c = 0; c < 4; ++c)
          GL16(Ap4[0] + k0 + (i64)(c * 8) * lda, AlB + c * 8 * BK);
      } else {
#pragma unroll
        for (int c = 0; c < 8; ++c)
          GL16(Ap4[c & 3] + k0 + (i64)(c * 4) * lda, AlB + c * 4 * BK);
      }
    } else {
#pragma unroll
      for (int j = 0; j < 4; ++j)
        *(short8*)(void*)&As[arow * 64 + (((ak0 + j) ^ (arow & 7)) << 3)] =
            pack8(fa[2 * j], fa[2 * j + 1]);
    }
    if constexpr (BK == 64) {
#pragma unroll
      for (int c = 0; c < 4; ++c)
        GL16(Bp4[0] + k0 + (i64)(c * 8) * ldb, BlB + c * 8 * BK);
    } else {
#pragma unroll
      for (int c = 0; c < 8; ++c)
        GL16(Bp4[c & 3] + k0 + (i64)(c * 4) * ldb, BlB + c * 4 * BK);
    }
    __syncthreads();  // compiler drains vmcnt/lgkm before barrier

#pragma unroll
    for (int h = 0; h < BK / 32; ++h) {    // 32-k halves, in k order
      const int sl = (h * 4 + kq) ^ rsw;
      short8 af[4], bf[4];
#pragma unroll
      for (int mf = 0; mf < 4; ++mf) {
        const int R = wr * 64 + mf * 16 + lr;
        af[mf] = *(const short8*)(const void*)&As[R * BK + (sl << 3)];
      }
#pragma unroll
      for (int nf = 0; nf < 4; ++nf) {
        const int R = wc * 64 + nf * 16 + lr;
        bf[nf] = *(const short8*)(const void*)&Bs[R * BK + (sl << 3)];
      }
#pragma unroll
      for (int mf = 0; mf < 4; ++mf)
#pragma unroll
        for (int nf = 0; nf < 4; ++nf)
          acc[mf][nf] = __builtin_amdgcn_mfma_f32_16x16x32_bf16(
              af[mf], bf[nf], acc[mf][nf], 0, 0, 0);
    }
  }

  // epilogue: D col = lane&15, row = (lane>>4)*4 + reg  [verified r2-r15]
  const int cl = lane & 15, rg = lane >> 4;
#pragma unroll
  for (int nf = 0; nf < 4; ++nf) {
    const i64 col = col0 + wc * 64 + nf * 16 + cl;
    const float bv = bi ? bi[col] : 0.f;
#pragma unroll
    for (int mf = 0; mf < 4; ++mf) {
#pragma unroll
      for (int r = 0; r < 4; ++r) {
        const i64 row = row0 + wr * 64 + mf * 16 + rg * 4 + r;
        float v = acc[mf][nf][r] + bv;
        if (relu) v = fmaxf(v, 0.f);
        if (OM & 1) Cf[row * (i64)ldc + col] = v;
        if (OM & 2) Cb[row * (i64)ldc + col] = f2bf(v);
      }
    }
  }
}

// ---------- fp32 -> bf16 streaming convert (8 elems/thread) ----------------
__global__ __launch_bounds__(256) void f2b_k(
    const float* __restrict__ x, unsigned short* __restrict__ y, i64 n)
{
  const i64 i = ((i64)blockIdx.x * 256 + threadIdx.x) * 8;
  if (i + 8 <= n) {
    float4 a = *(const float4*)(x + i);
    float4 b = *(const float4*)(x + i + 4);
    *(short8*)(void*)(y + i) = pack8(a, b);
  }
}

// ---------- weight transpose+convert: in[K][N] fp32 -> out[N][K] bf16 ------
__global__ __launch_bounds__(256) void wtrans_k(
    const float* __restrict__ in, unsigned short* __restrict__ out,
    int Kd, int Nd, i64 sIn, i64 sOut)
{
  __shared__ float t[32][33];
  in  += (i64)blockIdx.z * sIn;
  out += (i64)blockIdx.z * sOut;
  const int n0 = blockIdx.x * 32, k0 = blockIdx.y * 32;
  const int tx = threadIdx.x & 31, ty = threadIdx.x >> 5;
#pragma unroll
  for (int i = 0; i < 4; ++i)
    t[ty + 8 * i][tx] = in[(i64)(k0 + ty + 8 * i) * Nd + n0 + tx];
  __syncthreads();
#pragma unroll
  for (int i = 0; i < 4; ++i)
    out[(i64)(n0 + ty + 8 * i) * Kd + k0 + tx] = f2bf(t[tx][ty + 8 * i]);
}

// ---------- LayerNorm + exact GELU: one WAVE per (b,s) row, streaming ------
__global__ __launch_bounds__(256) void ln_gelu_k(
    const unsigned short* __restrict__ X, const float* __restrict__ gamma,
    const float* __restrict__ beta, unsigned short* __restrict__ Y)
{
  const int wv = threadIdx.x >> 6, l = threadIdx.x & 63;
  const i64 row = (i64)blockIdx.x * 4 + wv;       // row in [0, BATCH*SGS)
  const unsigned short* xr = X + row * H + l * 16;

  unsigned int Vp[8];
  {
    u32x4 a = *(const u32x4*)(const void*)(xr);
    u32x4 c = *(const u32x4*)(const void*)(xr + 8);
    Vp[0] = a[0]; Vp[1] = a[1]; Vp[2] = a[2]; Vp[3] = a[3];
    Vp[4] = c[0]; Vp[5] = c[1]; Vp[6] = c[2]; Vp[7] = c[3];
  }
  float s1 = 0.f, s2 = 0.f;
#pragma unroll
  for (int q = 0; q < 8; ++q) {
    float f0 = lo_bf(Vp[q]), f1 = hi_bf(Vp[q]);
    s1 += f0 + f1; s2 += f0 * f0 + f1 * f1;
  }
#pragma unroll
  for (int o = 1; o < 64; o <<= 1) {
    s1 += __shfl_xor(s1, o);
    s2 += __shfl_xor(s2, o);
  }
  const float mu = s1 * (1.f / H);
  const float var = s2 * (1.f / H) - mu * mu;
  const float rstd = rsqrtf(var + 1e-5f);
#pragma unroll
  for (int q = 0; q < 8; ++q) {
    float2 gv = *(const float2*)(gamma + l * 16 + q * 2);
    float2 bv = *(const float2*)(beta + l * 16 + q * 2);
    float f0 = (lo_bf(Vp[q]) - mu) * rstd * gv.x + bv.x;
    float f1 = (hi_bf(Vp[q]) - mu) * rstd * gv.y + bv.y;
    f0 = 0.5f * f0 * (1.f + erff(f0 * 0.70710678118654752f));
    f1 = 0.5f * f1 * (1.f + erff(f1 * 0.70710678118654752f));
    Vp[q] = pack_bf(f0, f1);
  }
  unsigned short* yr = Y + row * H + l * 16;
  u32x4 a, c;
  a[0] = Vp[0]; a[1] = Vp[1]; a[2] = Vp[2]; a[3] = Vp[3];
  c[0] = Vp[4]; c[1] = Vp[5]; c[2] = Vp[6]; c[3] = Vp[7];
  *(u32x4*)(void*)(yr) = a;
  *(u32x4*)(void*)(yr + 8) = c;
}

// ---------- orthonormalization (CGS dot-batched): one WAVE per batch row ---
__global__ __launch_bounds__(256) void gs_k(
    const unsigned short* __restrict__ X, unsigned short* __restrict__ Hb)
{
  const int wv = threadIdx.x >> 6, l = threadIdx.x & 63;
  const i64 b = (i64)blockIdx.x * 4 + wv;
  const unsigned short* xr = X + b * (i64)(SGS * H);

  unsigned int Vp[SGS][8];
#pragma unroll
  for (int s = 0; s < SGS; ++s) {
    u32x4 a = *(const u32x4*)(const void*)(xr + (i64)s * H + l * 16);
    u32x4 c = *(const u32x4*)(const void*)(xr + (i64)s * H + l * 16 + 8);
    Vp[s][0] = a[0]; Vp[s][1] = a[1]; Vp[s][2] = a[2]; Vp[s][3] = a[3];
    Vp[s][4] = c[0]; Vp[s][5] = c[1]; Vp[s][6] = c[2]; Vp[s][7] = c[3];
  }

  float dd[SGS];
#pragma unroll
  for (int i = 0; i < SGS; ++i) {
    float f[16];
#pragma unroll
    for (int q = 0; q < 8; ++q) {
      f[2 * q] = lo_bf(Vp[i][q]);
      f[2 * q + 1] = hi_bf(Vp[i][q]);
    }
    if (i > 0) {
      float cc[SGS > 1 ? SGS - 1 : 1];
#pragma unroll
      for (int j = 0; j < i; ++j) {
        cc[j] = 0.f;
#pragma unroll
        for (int q = 0; q < 8; ++q)
          cc[j] += f[2 * q] * lo_bf(Vp[j][q]) + f[2 * q + 1] * hi_bf(Vp[j][q]);
      }
#pragma unroll
      for (int o = 1; o < 64; o <<= 1)
#pragma unroll
        for (int j = 0; j < i; ++j) cc[j] += __shfl_xor(cc[j], o);
#pragma unroll
      for (int j = 0; j < i; ++j) {
        const float proj = (sqrtf(dd[j]) > EPS) ? cc[j] / dd[j] : 0.f;
#pragma unroll
        for (int q = 0; q < 8; ++q) {
          f[2 * q] -= proj * lo_bf(Vp[j][q]);
          f[2 * q + 1] -= proj * hi_bf(Vp[j][q]);
        }
      }
    }
    float nn = 0.f;
#pragma unroll
    for (int e = 0; e < 16; ++e) nn += f[e] * f[e];
#pragma unroll
    for (int o = 1; o < 64; o <<= 1) nn += __shfl_xor(nn, o);
    const float n = sqrtf(nn);
    if (n > EPS) {   // fallback branch statistically unreachable here
      const float inv = 1.f / n;
#pragma unroll
      for (int e = 0; e < 16; ++e) f[e] *= inv;
      dd[i] = nn * inv * inv;    // == dot(q_i,q_i) to ~1e-7
    } else {
      dd[i] = 1.f;
    }
#pragma unroll
    for (int q = 0; q < 8; ++q) Vp[i][q] = pack_bf(f[2 * q], f[2 * q + 1]);
  }

  unsigned short* hr = Hb + b * (i64)(SGS * H) + l * 16;
#pragma unroll
  for (int s = 0; s < SGS; ++s) {
    u32x4 a, c;
    a[0] = Vp[s][0]; a[1] = Vp[s][1]; a[2] = Vp[s][2]; a[3] = Vp[s][3];
    c[0] = Vp[s][4]; c[1] = Vp[s][5]; c[2] = Vp[s][6]; c[3] = Vp[s][7];
    *(u32x4*)(void*)(hr + (i64)s * H) = a;
    *(u32x4*)(void*)(hr + (i64)s * H + 8) = c;
  }
}

__device__ __forceinline__ float block_red(float v, float* scr) {
#pragma unroll
  for (int o = 32; o; o >>= 1) v += __shfl_down(v, o);
  int w = threadIdx.x >> 6;
  if ((threadIdx.x & 63) == 0) scr[w] = v;
  __syncthreads();
  v = scr[0] + scr[1] + scr[2] + scr[3];
  __syncthreads();
  return v;
}

// --------- loss: sum((p-h)^2), p bf16, h bf16 ------------------------------
__global__ __launch_bounds__(256) void loss_part_k(
    const unsigned short* __restrict__ p, const unsigned short* __restrict__ hb,
    float* __restrict__ part)
{
  __shared__ float scr[8];
  const i64 b = blockIdx.x;
  const int s = blockIdx.y;
  const i64 base = b * (i64)(SGS * H) + (i64)s * H;
  const int e = threadIdx.x * 4;
  ushort4 pv = *(const ushort4*)(p + base + e);
  ushort4 hv = *(const ushort4*)(hb + base + e);
  float d0 = b2f(pv.x) - b2f(hv.x), d1 = b2f(pv.y) - b2f(hv.y);
  float d2 = b2f(pv.z) - b2f(hv.z), d3 = b2f(pv.w) - b2f(hv.w);
  float acc = d0 * d0 + d1 * d1 + d2 * d2 + d3 * d3;
  acc = block_red(acc, scr);
  if (threadIdx.x == 0) part[(i64)s * BATCH + b] = acc;
}

__global__ __launch_bounds__(256) void loss_red_k(
    const float* __restrict__ part, float* __restrict__ losses)
{
  __shared__ float scr[8];
  const int s = blockIdx.x;
  float acc = 0.f;
  for (int e = threadIdx.x; e < BATCH; e += 256) acc += part[(i64)s * BATCH + e];
  acc = block_red(acc, scr);
  if (threadIdx.x == 0) losses[s] = acc / (float)((i64)BATCH * H);
}

__global__ void finalize_k(const float* __restrict__ losses,
                           const float* __restrict__ w, float* __restrict__ o)
{
  if (threadIdx.x == 0) {
    float t = 0.f;
#pragma unroll
    for (int s = 0; s < SGS; ++s) { float l = losses[s]; o[1 + s] = l; t += w[s] * l; }
    o[0] = t;
  }
}

// ---------------------------------------------------------------------------
extern "C" void kernel_launch(void* const* d_in, const int* in_sizes, int n_in,
                              void* d_out, int out_size, void* d_ws, size_t ws_size,
                              hipStream_t stream)
{
  (void)in_sizes; (void)n_in; (void)out_size;
  const float* sent    = (const float*)d_in[0];
  const float* decompW = (const float*)d_in[1];
  const float* ln_g    = (const float*)d_in[2];
  const float* ln_b    = (const float*)d_in[3];
  const float* pw1     = (const float*)d_in[4];
  const float* pb1     = (const float*)d_in[5];
  const float* pw2     = (const float*)d_in[6];
  const float* pb2     = (const float*)d_in[7];
  const float* qw1     = (const float*)d_in[8];
  const float* qb1     = (const float*)d_in[9];
  const float* qw2     = (const float*)d_in[10];
  const float* qb2     = (const float*)d_in[11];
  const float* fw1     = (const float*)d_in[12];
  const float* fb1     = (const float*)d_in[13];
  const float* fw2     = (const float*)d_in[14];
  const float* fb2     = (const float*)d_in[15];
  const float* semw    = (const float*)d_in[16];
  float* out = (float*)d_out;

  float* ws = (float*)d_ws;
  const dim3 blk(256);
  const i64 HH = (i64)H * H;
  const i64 SH = (i64)SGS * H;
  const i64 SLABf = (i64)BATCH * SGS * H / 2;      // 14,680,064 fl per bf16 slab

  // full tier needs 3 slabs + W slab + part: 47,738,912 floats = 190.96 MB
  const bool full = ws_size >= (size_t)(3 * SLABf + 3670016 + 28704) * 4;

  if (full) {
    unsigned short* U1 = (unsigned short*)ws;                   // X->H; later fw1t/fw2t/T
    unsigned short* U2 = (unsigned short*)(ws + SLABf);         // sentb -> z1 / p1
    unsigned short* Pb = (unsigned short*)(ws + 2 * SLABf);     // decompWt -> z2 -> p
    unsigned short* W  = (unsigned short*)(ws + 3 * SLABf);     // [7][1024][1024]
    float* part   = ws + 3 * SLABf + 3670016;                   // [7][4096]
    float* losses = part + (i64)SGS * BATCH;
    unsigned short* decompWt = Pb;                              // dies before z2
    unsigned short* sentb = U2;                                 // bf16 sent (dies before z1)
    unsigned short* fw1t = U1;                                  // after H dies
    unsigned short* fw2t = U1 + (i64)2 * H * SGS * H;           // +14,680,064 sh
    unsigned short* T    = fw2t + (i64)H * 2 * H;               // +2,097,152 sh

    // 1) decompWt; sentb = bf16(sent); X = sentb @ decompWt -> U1 (gload path)
    wtrans_k<<<dim3(224, 32, 1), blk, 0, stream>>>(decompW, decompWt, H, SGS * H, 0, 0);
    f2b_k<<<dim3((unsigned)((i64)BATCH * H / 2048)), blk, 0, stream>>>(
        sent, sentb, (i64)BATCH * H);
    ggemm_k<1, 2, 64><<<dim3(56, BATCH / 128, 1), blk, 0, stream>>>(
        sentb, H, 0, decompWt, H, 0, nullptr, U1, SGS * H, 0, nullptr, 0, H, 0);
    // 2) LN+GELU then GS, both in place (split: VGPR discipline, R14 lesson)
    ln_gelu_k<<<dim3(BATCH * SGS / 4), blk, 0, stream>>>(U1, ln_g, ln_b, U1);
    gs_k<<<dim3(BATCH / 4), blk, 0, stream>>>(U1, U1);
    // 3) SPR stages, full batch (1792 blocks each), one wtrans per weight
    wtrans_k<<<dim3(32, 32, SGS), blk, 0, stream>>>(pw1, W, H, H, HH, HH);
    ggemm_k<1, 2, 64><<<dim3(8, BATCH / 128, SGS), blk, 0, stream>>>(
        U1, SH, H, W, H, HH, nullptr, U2, SH, H, pb1, H, H, 1);  // overwrites sentb (dead)
    wtrans_k<<<dim3(32, 32, SGS), blk, 0, stream>>>(pw2, W, H, H, HH, HH);
    ggemm_k<1, 2, 64><<<dim3(8, BATCH / 128, SGS), blk, 0, stream>>>(
        U2, SH, H, W, H, HH, nullptr, Pb, SH, H, pb2, H, H, 0);  // overwrites decompWt (dead)
    wtrans_k<<<dim3(32, 32, SGS), blk, 0, stream>>>(qw1, W, H, H, HH, HH);
    ggemm_k<1, 2, 64><<<dim3(8, BATCH / 128, SGS), blk, 0, stream>>>(
        Pb, SH, H, W, H, HH, nullptr, U2, SH, H, qb1, H, H, 1);
    wtrans_k<<<dim3(32, 32, SGS), blk, 0, stream>>>(qw2, W, H, H, HH, HH);
    ggemm_k<1, 2, 64><<<dim3(8, BATCH / 128, SGS), blk, 0, stream>>>(
        U2, SH, H, W, H, HH, nullptr, Pb, SH, H, qb2, H, H, 0);  // p -> Pb (z2 dead)
    // 4) loss (p in Pb vs H in U1)
    loss_part_k<<<dim3(BATCH, SGS), blk, 0, stream>>>(Pb, U1, part);
    // 5) fusion: H dead -> fw1t/fw2t/T into U1; BK=128 (low-occupancy GEMMs)
    wtrans_k<<<dim3(64, 224, 1), blk, 0, stream>>>(fw1, fw1t, SGS * H, 2 * H, 0, 0);
    wtrans_k<<<dim3(32, 64, 1), blk, 0, stream>>>(fw2, fw2t, 2 * H, H, 0, 0);
    ggemm_k<1, 2, 128><<<dim3(16, BATCH / 128, 1), blk, 0, stream>>>(
        Pb, SH, 0, fw1t, SGS * H, 0, nullptr, T, 2 * H, 0, fb1, 0, SGS * H, 1);
    ggemm_k<1, 1, 128><<<dim3(8, BATCH / 128, 1), blk, 0, stream>>>(
        T, 2 * H, 0, fw2t, 2 * H, 0, out, nullptr, H, 0, fb2, 0, 2 * H, 0);
    loss_red_k<<<dim3(SGS), blk, 0, stream>>>(part, losses);
    finalize_k<<<dim3(1), dim3(64), 0, stream>>>(losses, semw, out + (i64)BATCH * H);
    return;
  }

  // -------- fallback: proven R7 layout (180.47MB), swizzled --------
  const int BC = 2048;
  unsigned short* W        = (unsigned short*)(ws);             // [7][1024][1024] (reused)
  unsigned short* decompWt = (unsigned short*)(ws + 3670016);   // [7168][1024]
  unsigned short* fw1t     = (unsigned short*)(ws + 7340032);   // [2048][7168]
  unsigned short* fw2t     = (unsigned short*)(ws + 14680064);  // [1024][2048]
  unsigned short* XH       = (unsigned short*)(ws + 15728640);  // chunk [2048][7168]
  unsigned short* Y        = (unsigned short*)(ws + 23068672);  // chunk [2048][7168]
  unsigned short* Pb       = (unsigned short*)(ws + 30408704);  // FULL [4096][7168]
  float* part   = ws + 45088768;                                // [7][4096]
  float* losses = part + (i64)SGS * BATCH;
  unsigned short* T = Y;

  wtrans_k<<<dim3(224, 32, 1), blk, 0, stream>>>(decompW, decompWt, H, SGS * H, 0, 0);
  wtrans_k<<<dim3(64, 224, 1), blk, 0, stream>>>(fw1, fw1t, SGS * H, 2 * H, 0, 0);
  wtrans_k<<<dim3(32, 64, 1), blk, 0, stream>>>(fw2, fw2t, 2 * H, H, 0, 0);

  for (int c = 0; c < BATCH / BC; ++c) {
    const i64 r0 = (i64)c * BC;
    unsigned short* Pc = Pb + r0 * SH;
    ggemm_k<0, 2, 64><<<dim3(56, BC / 128, 1), blk, 0, stream>>>(
        sent + r0 * H, H, 0, decompWt, H, 0, nullptr, XH, SGS * H, 0,
        nullptr, 0, H, 0);
    ln_gelu_k<<<dim3(BC * SGS / 4), blk, 0, stream>>>(XH, ln_g, ln_b, XH);
    gs_k<<<dim3(BC / 4), blk, 0, stream>>>(XH, XH);
    wtrans_k<<<dim3(32, 32, SGS), blk, 0, stream>>>(pw1, W, H, H, HH, HH);
    ggemm_k<1, 2, 64><<<dim3(8, BC / 128, SGS), blk, 0, stream>>>(
        XH, SH, H, W, H, HH, nullptr, Y, SH, H, pb1, H, H, 1);
    wtrans_k<<<dim3(32, 32, SGS), blk, 0, stream>>>(pw2, W, H, H, HH, HH);
    ggemm_k<1, 2, 64><<<dim3(8, BC / 128, SGS), blk, 0, stream>>>(
        Y, SH, H, W, H, HH, nullptr, Pc, SH, H, pb2, H, H, 0);
    wtrans_k<<<dim3(32, 32, SGS), blk, 0, stream>>>(qw1, W, H, H, HH, HH);
    ggemm_k<1, 2, 64><<<dim3(8, BC / 128, SGS), blk, 0, stream>>>(
        Pc, SH, H, W, H, HH, nullptr, Y, SH, H, qb1, H, H, 1);
    wtrans_k<<<dim3(32, 32, SGS), blk, 0, stream>>>(qw2, W, H, H, HH, HH);
    ggemm_k<1, 2, 64><<<dim3(8, BC / 128, SGS), blk, 0, stream>>>(
        Y, SH, H, W, H, HH, nullptr, Pc, SH, H, qb2, H, H, 0);
    loss_part_k<<<dim3(BC, SGS), blk, 0, stream>>>(Pc, XH, part + r0);
  }

  ggemm_k<1, 2, 128><<<dim3(16, BATCH / 128, 1), blk, 0, stream>>>(
      Pb, SH, 0, fw1t, SGS * H, 0, nullptr, T, 2 * H, 0, fb1, 0, SGS * H, 1);
  ggemm_k<1, 1, 128><<<dim3(8, BATCH / 128, 1), blk, 0, stream>>>(
      T, 2 * H, 0, fw2t, 2 * H, 0, out, nullptr, H, 0, fb2, 0, 2 * H, 0);

  loss_red_k<<<dim3(SGS), blk, 0, stream>>>(part, losses);
  finalize_k<<<dim3(1), dim3(64), 0, stream>>>(losses, semw, out + (i64)BATCH * H);
}